// Round 1
// baseline (446.952 us; speedup 1.0000x reference)
//
#include <hip/hip_runtime.h>
#include <math.h>

namespace {

constexpr int N_PTS  = 1000000;
constexpr int C_CLS  = 20;
constexpr int N_B    = 4;
constexpr int L_LAB  = 200;
constexpr int LW     = L_LAB + 1;   // 201
constexpr int N_INST = 64;
constexpr int M_PTS  = 300000;
constexpr int IGN    = -100;
constexpr int PREP   = 128;

// ---- workspace layout (bytes) ----
constexpr size_t OFF_G       = 0;      // 8 doubles: [nll, semcnt, dist, dir, validcnt]
constexpr size_t OFF_INTER   = 64;     // 64 doubles
constexpr size_t OFF_UP      = 576;
constexpr size_t OFF_UG      = 1088;
constexpr size_t OFF_WBS     = 1600;
constexpr size_t OFF_SN      = 2112;
constexpr size_t OFF_HFULL   = 2624;   // 804 ints
constexpr size_t OFF_HMASK   = 5840;   // 804 ints
constexpr size_t OFF_MODE    = 9056;   // 64 ints
constexpr size_t OFF_FLAGS   = 9312;   // 64 ints
constexpr size_t ZERO_BYTES  = 9568;
constexpr size_t OFF_META    = 9600;   // 300000 ints
constexpr size_t WS_REQUIRED = OFF_META + (size_t)M_PTS * 4;

__device__ __forceinline__ float waveSum(float v) {
  #pragma unroll
  for (int off = 32; off > 0; off >>= 1) v += __shfl_down(v, off, 64);
  return v;
}

// K1: per-instance label histogram over its proposal range -> mode_id (argmax, first-index ties)
__global__ __launch_bounds__(256) void k_mode(const int* __restrict__ prop_idx,
                                              const int* __restrict__ prop_off,
                                              const int* __restrict__ inst_lab,
                                              int* __restrict__ mode_out) {
  __shared__ int hist[LW];
  const int i = blockIdx.x;
  for (int t = threadIdx.x; t < LW; t += blockDim.x) hist[t] = 0;
  __syncthreads();
  const int beg = prop_off[i], end = prop_off[i + 1];
  for (int t = beg + threadIdx.x; t < end; t += blockDim.x) {
    const int p  = prop_idx[2 * t + 1];
    const int il = inst_lab[p];
    const int lab = (il == IGN) ? 0 : (il + 1);
    atomicAdd(&hist[lab], 1);
  }
  __syncthreads();
  if (threadIdx.x == 0) {
    int best = 0, bi = 0;
    for (int c = 0; c < LW; ++c)
      if (hist[c] > best) { best = hist[c]; bi = c; }
    mode_out[i] = bi;   // all-zero hist -> 0, matches jnp.argmax
  }
}

// K2: hist_full[B][LW] over all N points (LDS histogram per block, atomic flush)
__global__ __launch_bounds__(256) void k_hist_full(const int* __restrict__ inst_lab,
                                                   const int* __restrict__ batch_off,
                                                   int* __restrict__ hist_full) {
  __shared__ int hist[N_B * LW];
  for (int t = threadIdx.x; t < N_B * LW; t += blockDim.x) hist[t] = 0;
  __syncthreads();
  const int b1 = batch_off[1], b2 = batch_off[2], b3 = batch_off[3];
  for (int p = blockIdx.x * blockDim.x + threadIdx.x; p < N_PTS; p += gridDim.x * blockDim.x) {
    const int il = inst_lab[p];
    const int lab = (il == IGN) ? 0 : (il + 1);
    int pb = 0;                       // searchsorted(batch_off, p, 'right')-1, clipped
    if (p >= b1) pb = 1;
    if (p >= b2) pb = 2;
    if (p >= b3) pb = 3;
    atomicAdd(&hist[pb * LW + lab], 1);
  }
  __syncthreads();
  for (int t = threadIdx.x; t < N_B * LW; t += blockDim.x)
    if (hist[t]) atomicAdd(&hist_full[t], hist[t]);
}

// K3: hist_mask[B][LW] over M masked points + packed per-j metadata
__global__ __launch_bounds__(256) void k_hist_mask(const int* __restrict__ obj_idx,
                                                   const int* __restrict__ inst_lab,
                                                   const int* __restrict__ sem_lab,
                                                   const int* __restrict__ batch_ids,
                                                   int* __restrict__ hist_mask,
                                                   int* __restrict__ meta,
                                                   int write_meta) {
  __shared__ int hist[N_B * LW];
  for (int t = threadIdx.x; t < N_B * LW; t += blockDim.x) hist[t] = 0;
  __syncthreads();
  for (int j = blockIdx.x * blockDim.x + threadIdx.x; j < M_PTS; j += gridDim.x * blockDim.x) {
    const int o  = obj_idx[j];
    const int il = inst_lab[o];
    const int ml = (il == IGN) ? 0 : (il + 1);     // [0,200] -> 8 bits
    const int b  = batch_ids[j];                   // [0,3]   -> 2 bits
    atomicAdd(&hist[b * LW + ml], 1);
    if (write_meta) {
      const int sm = sem_lab[o];                   // [0,19]  -> 5 bits
      meta[j] = ml | (sm << 8) | (b << 13);
    }
  }
  __syncthreads();
  for (int t = threadIdx.x; t < N_B * LW; t += blockDim.x)
    if (hist[t]) atomicAdd(&hist_mask[t], hist[t]);
}

// K4: per-instance scalars -> packed flags {mode[0:8], skip[8], pos[9], batch[10:12], seg[12:17]}
__global__ void k_inst(const int* __restrict__ mode,
                       const int* __restrict__ hist_full,
                       const int* __restrict__ hist_mask,
                       const int* __restrict__ inst_batch_ids,
                       const int* __restrict__ inst_seg,
                       int* __restrict__ instflags) {
  const int i = threadIdx.x;
  if (i >= N_INST) return;
  const int m   = mode[i];
  const int b   = inst_batch_ids[i];
  const int seg = inst_seg[i];
  const bool skip = (m == 0) || (seg <= 3);
  const float num = (float)hist_mask[b * LW + m];
  const float den = (float)hist_full[b * LW + m];
  const float cover = (den > 0.f) ? (num / den) : 0.f;
  const bool pos = (!skip) && (cover > 0.3f);
  instflags[i] = m | (skip ? 0x100 : 0) | (pos ? 0x200 : 0) | (b << 10) | (seg << 12);
}

// K5: per-point losses (semantic NLL, offset L1, offset dir), 5 global double sums
__global__ __launch_bounds__(256) void k_point(const float* __restrict__ scores,
                                               const float* __restrict__ pt_off,
                                               const float* __restrict__ info,
                                               const float* __restrict__ coords,
                                               const int* __restrict__ sem_lab,
                                               const int* __restrict__ inst_lab,
                                               double* __restrict__ g) {
  float s_nll = 0.f, s_cnt = 0.f, s_dist = 0.f, s_dir = 0.f, s_val = 0.f;
  for (int p = blockIdx.x * blockDim.x + threadIdx.x; p < N_PTS; p += gridDim.x * blockDim.x) {
    // --- log-softmax NLL, C=20 via 5x float4 (rows 80B -> 16B aligned) ---
    const float4* r4 = reinterpret_cast<const float4*>(scores + (size_t)p * C_CLS);
    float x[C_CLS];
    #pragma unroll
    for (int q = 0; q < C_CLS / 4; ++q) {
      const float4 v = r4[q];
      x[4 * q + 0] = v.x; x[4 * q + 1] = v.y; x[4 * q + 2] = v.z; x[4 * q + 3] = v.w;
    }
    float mx = x[0];
    #pragma unroll
    for (int c = 1; c < C_CLS; ++c) mx = fmaxf(mx, x[c]);
    float se = 0.f;
    #pragma unroll
    for (int c = 0; c < C_CLS; ++c) se += __expf(x[c] - mx);
    const float lse = mx + __logf(se);
    const int lab = sem_lab[p];
    const bool sv = (lab != IGN);
    const float nll = lse - x[sv ? lab : 0];
    if (sv) { s_nll += nll; s_cnt += 1.f; }
    // --- offset losses ---
    const float cx = coords[3 * p + 0], cy = coords[3 * p + 1], cz = coords[3 * p + 2];
    const float gx = info[9 * (size_t)p + 0] - cx;
    const float gy = info[9 * (size_t)p + 1] - cy;
    const float gz = info[9 * (size_t)p + 2] - cz;
    const float ox = pt_off[3 * p + 0], oy = pt_off[3 * p + 1], oz = pt_off[3 * p + 2];
    const int il = inst_lab[p];
    if (il != IGN) {
      s_val  += 1.f;
      s_dist += fabsf(ox - gx) + fabsf(oy - gy) + fabsf(oz - gz);
      const float gn = sqrtf(gx * gx + gy * gy + gz * gz) + 1e-8f;
      const float pn = sqrtf(ox * ox + oy * oy + oz * oz) + 1e-8f;
      s_dir += -((gx * ox + gy * oy + gz * oz) / (gn * pn));
    }
  }
  __shared__ float red[5][4];
  float vals[5] = { s_nll, s_cnt, s_dist, s_dir, s_val };
  const int lane = threadIdx.x & 63, wv = threadIdx.x >> 6;
  #pragma unroll
  for (int k = 0; k < 5; ++k) {
    const float t = waveSum(vals[k]);
    if (lane == 0) red[k][wv] = t;
  }
  __syncthreads();
  if (threadIdx.x < 5) {
    const float s = red[threadIdx.x][0] + red[threadIdx.x][1] + red[threadIdx.x][2] + red[threadIdx.x][3];
    atomicAdd(&g[threadIdx.x], (double)s);
  }
}

// K6: mask dice/BCE partial sums per instance. All logit uses gated by w -> skip load when w==0.
template <bool USE_META>
__global__ __launch_bounds__(256) void k_mask(const float* __restrict__ logits,
                                              const int* __restrict__ meta,
                                              const int* __restrict__ obj_idx,
                                              const int* __restrict__ inst_lab,
                                              const int* __restrict__ sem_lab,
                                              const int* __restrict__ batch_ids,
                                              const int* __restrict__ instflags,
                                              double* __restrict__ i_inter,
                                              double* __restrict__ i_up,
                                              double* __restrict__ i_ug,
                                              double* __restrict__ i_wbs,
                                              double* __restrict__ i_sn) {
  const int i  = blockIdx.y;
  const int fl = instflags[i];
  const int  mode = fl & 0xFF;
  const bool skip = (fl >> 8) & 1;
  const bool pos  = (fl >> 9) & 1;
  const int  bi   = (fl >> 10) & 3;
  const int  seg  = (fl >> 12) & 31;
  const float* row = logits + (size_t)i * M_PTS;
  float inter = 0.f, up = 0.f, ug = 0.f, wbs = 0.f, sn = 0.f;
  for (int j = blockIdx.x * blockDim.x + threadIdx.x; j < M_PTS; j += gridDim.x * blockDim.x) {
    int ml, sm, b;
    if (USE_META) {
      const int md = meta[j];
      ml = md & 0xFF; sm = (md >> 8) & 31; b = (md >> 13) & 3;
    } else {
      const int o  = obj_idx[j];
      const int il = inst_lab[o];
      ml = (il == IGN) ? 0 : (il + 1);
      sm = sem_lab[o];
      b  = batch_ids[j];
    }
    const bool w = (b == bi) && (skip || (sm == seg));
    if (w) {                         // weights==wb (binary); every term has a wb/w factor
      const float x  = row[j];
      const bool  gt = pos && (ml == mode);
      const float pr = 1.f / (1.f + __expf(-x));
      up  += pr * pr;
      wbs += 1.f;
      const float sp = fmaxf(x, 0.f) + log1pf(__expf(-fabsf(x)));  // stable softplus
      sn  += sp - (gt ? x : 0.f);
      if (gt) { inter += pr; ug += 1.f; }
    }
  }
  __shared__ float red[5][4];
  float vals[5] = { inter, up, ug, wbs, sn };
  const int lane = threadIdx.x & 63, wv = threadIdx.x >> 6;
  #pragma unroll
  for (int k = 0; k < 5; ++k) {
    const float t = waveSum(vals[k]);
    if (lane == 0) red[k][wv] = t;
  }
  __syncthreads();
  if (threadIdx.x < 5) {
    const float s = red[threadIdx.x][0] + red[threadIdx.x][1] + red[threadIdx.x][2] + red[threadIdx.x][3];
    double* dst = (threadIdx.x == 0) ? (i_inter + i)
                : (threadIdx.x == 1) ? (i_up + i)
                : (threadIdx.x == 2) ? (i_ug + i)
                : (threadIdx.x == 3) ? (i_wbs + i)
                                     : (i_sn + i);
    atomicAdd(dst, (double)s);
  }
}

// K7: combine everything into the scalar loss
__global__ void k_final(const double* __restrict__ g,
                        const double* __restrict__ i_inter,
                        const double* __restrict__ i_up,
                        const double* __restrict__ i_ug,
                        const double* __restrict__ i_wbs,
                        const double* __restrict__ i_sn,
                        const int* __restrict__ instflags,
                        const int* __restrict__ epoch,
                        float* __restrict__ out) {
  if (threadIdx.x != 0 || blockIdx.x != 0) return;
  double loss = g[0] / fmax(g[1], 1.0);            // semantic
  const double vsum = g[4] + 1e-6;
  loss += g[2] / vsum + g[3] / vsum;               // offset norm + dir
  if (epoch[0] > PREP) {
    double sn = 0.0, wsum = 0.0, dice = 0.0, dcnt = 0.0;
    for (int i = 0; i < N_INST; ++i) {
      wsum += i_wbs[i];
      sn   += i_sn[i];
      const bool skip = (instflags[i] >> 8) & 1;
      if (!skip && i_wbs[i] > 0.0) {
        const double un = i_up[i] + i_ug[i] + 1e-5;
        dice += 1.0 - 2.0 * i_inter[i] / un;
        dcnt += 1.0;
      }
    }
    loss += sn / (wsum + 1e-6) + dice / (dcnt + 1e-6);
  }
  out[0] = (float)loss;
}

} // anonymous namespace

extern "C" void kernel_launch(void* const* d_in, const int* in_sizes, int n_in,
                              void* d_out, int out_size, void* d_ws, size_t ws_size,
                              hipStream_t stream) {
  const float* semantic_scores  = (const float*)d_in[0];
  const float* pt_offsets       = (const float*)d_in[1];
  const float* instance_info    = (const float*)d_in[2];
  const float* coords           = (const float*)d_in[3];
  const float* mask_logits      = (const float*)d_in[4];
  const int*   semantic_labels  = (const int*)d_in[5];
  const int*   instance_labels  = (const int*)d_in[6];
  const int*   object_idxs      = (const int*)d_in[7];
  const int*   proposals_idx    = (const int*)d_in[8];
  const int*   proposals_off    = (const int*)d_in[9];
  const int*   inst_batch_ids   = (const int*)d_in[10];
  const int*   batch_ids        = (const int*)d_in[11];
  const int*   batch_offsets    = (const int*)d_in[12];
  const int*   inst_seg         = (const int*)d_in[13];
  const int*   epoch            = (const int*)d_in[14];
  float* out = (float*)d_out;

  char* w = (char*)d_ws;
  double* g        = (double*)(w + OFF_G);
  double* i_inter  = (double*)(w + OFF_INTER);
  double* i_up     = (double*)(w + OFF_UP);
  double* i_ug     = (double*)(w + OFF_UG);
  double* i_wbs    = (double*)(w + OFF_WBS);
  double* i_sn     = (double*)(w + OFF_SN);
  int* hist_full   = (int*)(w + OFF_HFULL);
  int* hist_mask   = (int*)(w + OFF_HMASK);
  int* mode        = (int*)(w + OFF_MODE);
  int* instflags   = (int*)(w + OFF_FLAGS);
  int* meta        = (int*)(w + OFF_META);

  const bool use_meta = (ws_size >= WS_REQUIRED);

  hipMemsetAsync(d_ws, 0, ZERO_BYTES, stream);

  k_mode<<<N_INST, 256, 0, stream>>>(proposals_idx, proposals_off, instance_labels, mode);
  k_hist_full<<<256, 256, 0, stream>>>(instance_labels, batch_offsets, hist_full);
  k_hist_mask<<<128, 256, 0, stream>>>(object_idxs, instance_labels, semantic_labels,
                                       batch_ids, hist_mask, meta, use_meta ? 1 : 0);
  k_inst<<<1, 64, 0, stream>>>(mode, hist_full, hist_mask, inst_batch_ids, inst_seg, instflags);
  k_point<<<2048, 256, 0, stream>>>(semantic_scores, pt_offsets, instance_info, coords,
                                    semantic_labels, instance_labels, g);
  dim3 mgrid(40, N_INST);
  if (use_meta) {
    k_mask<true><<<mgrid, 256, 0, stream>>>(mask_logits, meta, object_idxs, instance_labels,
                                            semantic_labels, batch_ids, instflags,
                                            i_inter, i_up, i_ug, i_wbs, i_sn);
  } else {
    k_mask<false><<<mgrid, 256, 0, stream>>>(mask_logits, meta, object_idxs, instance_labels,
                                             semantic_labels, batch_ids, instflags,
                                             i_inter, i_up, i_ug, i_wbs, i_sn);
  }
  k_final<<<1, 64, 0, stream>>>(g, i_inter, i_up, i_ug, i_wbs, i_sn, instflags, epoch, out);
}

// Round 2
// 361.045 us; speedup vs baseline: 1.2379x; 1.2379x over previous
//
#include <hip/hip_runtime.h>
#include <math.h>

namespace {

constexpr int N_PTS  = 1000000;
constexpr int C_CLS  = 20;
constexpr int N_B    = 4;
constexpr int L_LAB  = 200;
constexpr int LW     = L_LAB + 1;   // 201
constexpr int N_INST = 64;
constexpr int M_PTS  = 300000;
constexpr int IGN    = -100;
constexpr int PREP   = 128;

// ---- workspace layout (bytes) ----
constexpr size_t OFF_G       = 0;      // 8 doubles: [nll, semcnt, dist, dir, validcnt]
constexpr size_t OFF_INTER   = 64;     // 64 doubles
constexpr size_t OFF_UP      = 576;
constexpr size_t OFF_UG      = 1088;
constexpr size_t OFF_WBS     = 1600;
constexpr size_t OFF_SN      = 2112;
constexpr size_t OFF_HFULL   = 2624;   // 804 ints
constexpr size_t OFF_HMASK   = 5840;   // 804 ints
constexpr size_t OFF_MODE    = 9056;   // 64 ints
constexpr size_t ZERO_BYTES  = 9312;
constexpr size_t OFF_META    = 9344;   // 300000 ushorts (8B aligned)
constexpr size_t WS_REQUIRED = OFF_META + (size_t)M_PTS * 2;

__device__ __forceinline__ float waveSum(float v) {
  #pragma unroll
  for (int off = 32; off > 0; off >>= 1) v += __shfl_down(v, off, 64);
  return v;
}

// ---------------------------------------------------------------------------
// K1 "prep": one dispatch, three independent jobs split by blockIdx.x.
//   blocks [0,64)    : per-instance proposal-label histogram -> mode_id
//   blocks [64,192)  : hist_mask[B][LW] over M masked points + meta16[j]
//   blocks [192,448) : hist_full[B][LW] over all N points
// ---------------------------------------------------------------------------
constexpr int PB_MODE = 64;
constexpr int PB_HM   = 128;
constexpr int PB_HF   = 256;
constexpr int PREP_BLOCKS = PB_MODE + PB_HM + PB_HF;

__global__ __launch_bounds__(256) void k_prep(const int* __restrict__ prop_idx,
                                              const int* __restrict__ prop_off,
                                              const int* __restrict__ inst_lab,
                                              const int* __restrict__ sem_lab,
                                              const int* __restrict__ obj_idx,
                                              const int* __restrict__ batch_ids,
                                              const int* __restrict__ batch_off,
                                              int* __restrict__ mode_out,
                                              int* __restrict__ hist_mask,
                                              int* __restrict__ hist_full,
                                              unsigned short* __restrict__ meta,
                                              int write_meta) {
  __shared__ int hist[N_B * LW];
  const int bx = blockIdx.x;

  if (bx < PB_MODE) {
    // ---- per-instance mode over its proposal range ----
    const int i = bx;
    for (int t = threadIdx.x; t < LW; t += blockDim.x) hist[t] = 0;
    __syncthreads();
    const int beg = prop_off[i], end = prop_off[i + 1];
    const int2* pi2 = reinterpret_cast<const int2*>(prop_idx);
    for (int t = beg + threadIdx.x; t < end; t += blockDim.x) {
      const int p  = pi2[t].y;
      const int il = inst_lab[p];
      const int lab = (il == IGN) ? 0 : (il + 1);
      atomicAdd(&hist[lab], 1);
    }
    __syncthreads();
    if (threadIdx.x == 0) {
      int best = 0, bi = 0;
      for (int c = 0; c < LW; ++c)
        if (hist[c] > best) { best = hist[c]; bi = c; }
      mode_out[i] = bi;   // all-zero hist -> 0, matches jnp.argmax
    }
  } else if (bx < PB_MODE + PB_HM) {
    // ---- hist_mask over M masked points + packed per-j metadata ----
    for (int t = threadIdx.x; t < N_B * LW; t += blockDim.x) hist[t] = 0;
    __syncthreads();
    const int blk = bx - PB_MODE;
    for (int j = blk * blockDim.x + threadIdx.x; j < M_PTS; j += PB_HM * blockDim.x) {
      const int o  = obj_idx[j];
      const int il = inst_lab[o];
      const int ml = (il == IGN) ? 0 : (il + 1);     // 8 bits
      const int b  = batch_ids[j];                   // 2 bits
      atomicAdd(&hist[b * LW + ml], 1);
      if (write_meta) {
        const int sm = sem_lab[o];                   // 5 bits
        meta[j] = (unsigned short)(ml | (sm << 8) | (b << 13));
      }
    }
    __syncthreads();
    for (int t = threadIdx.x; t < N_B * LW; t += blockDim.x)
      if (hist[t]) atomicAdd(&hist_mask[t], hist[t]);
  } else {
    // ---- hist_full over all N points ----
    for (int t = threadIdx.x; t < N_B * LW; t += blockDim.x) hist[t] = 0;
    __syncthreads();
    const int b1 = batch_off[1], b2 = batch_off[2], b3 = batch_off[3];
    const int blk = bx - PB_MODE - PB_HM;
    for (int p = blk * blockDim.x + threadIdx.x; p < N_PTS; p += PB_HF * blockDim.x) {
      const int il = inst_lab[p];
      const int lab = (il == IGN) ? 0 : (il + 1);
      int pb = 0;
      if (p >= b1) pb = 1;
      if (p >= b2) pb = 2;
      if (p >= b3) pb = 3;
      atomicAdd(&hist[pb * LW + lab], 1);
    }
    __syncthreads();
    for (int t = threadIdx.x; t < N_B * LW; t += blockDim.x)
      if (hist[t]) atomicAdd(&hist_full[t], hist[t]);
  }
}

// ---------------------------------------------------------------------------
// K2: per-point losses, 4 consecutive points/thread, fully vectorized loads.
// ---------------------------------------------------------------------------
__global__ __launch_bounds__(256) void k_point(const float* __restrict__ scores,
                                               const float* __restrict__ pt_off,
                                               const float* __restrict__ info,
                                               const float* __restrict__ coords,
                                               const int* __restrict__ sem_lab,
                                               const int* __restrict__ inst_lab,
                                               double* __restrict__ g) {
  float s_nll = 0.f, s_cnt = 0.f, s_dist = 0.f, s_dir = 0.f, s_val = 0.f;
  const int gid = blockIdx.x * blockDim.x + threadIdx.x;   // one group of 4 points
  const int p0  = gid * 4;
  if (p0 < N_PTS) {
    // ---- vector loads for the 4-point group ----
    const int4 sl4 = *reinterpret_cast<const int4*>(sem_lab + p0);
    const int4 il4 = *reinterpret_cast<const int4*>(inst_lab + p0);
    const float4* c4 = reinterpret_cast<const float4*>(coords + (size_t)p0 * 3);
    const float4 ca = c4[0], cb = c4[1], cc = c4[2];
    const float4* o4 = reinterpret_cast<const float4*>(pt_off + (size_t)p0 * 3);
    const float4 oa = o4[0], ob = o4[1], oc = o4[2];
    const float4* i4 = reinterpret_cast<const float4*>(info + (size_t)p0 * 9);
    const float4 f0 = i4[0], f2 = i4[2], f4 = i4[4], f5 = i4[5], f6 = i4[6], f7 = i4[7];
    // per-point (cx,cy,cz), (ox,oy,oz), (ix,iy,iz)
    const float cx[4] = { ca.x, ca.w, cb.z, cc.y };
    const float cy[4] = { ca.y, cb.x, cb.w, cc.z };
    const float cz[4] = { ca.z, cb.y, cc.x, cc.w };
    const float ox[4] = { oa.x, oa.w, ob.z, oc.y };
    const float oy[4] = { oa.y, ob.x, ob.w, oc.z };
    const float oz[4] = { oa.z, ob.y, oc.x, oc.w };
    const float ix[4] = { f0.x, f2.y, f4.z, f6.w };
    const float iy[4] = { f0.y, f2.z, f4.w, f7.x };
    const float iz[4] = { f0.z, f2.w, f5.x, f7.y };
    const int sl[4] = { sl4.x, sl4.y, sl4.z, sl4.w };
    const int il[4] = { il4.x, il4.y, il4.z, il4.w };

    #pragma unroll
    for (int k = 0; k < 4; ++k) {
      const int p = p0 + k;
      // --- log-softmax NLL, C=20 via 5x float4 ---
      const float4* r4 = reinterpret_cast<const float4*>(scores + (size_t)p * C_CLS);
      float x[C_CLS];
      #pragma unroll
      for (int q = 0; q < C_CLS / 4; ++q) {
        const float4 v = r4[q];
        x[4 * q + 0] = v.x; x[4 * q + 1] = v.y; x[4 * q + 2] = v.z; x[4 * q + 3] = v.w;
      }
      float mx = x[0];
      #pragma unroll
      for (int c = 1; c < C_CLS; ++c) mx = fmaxf(mx, x[c]);
      float se = 0.f;
      #pragma unroll
      for (int c = 0; c < C_CLS; ++c) se += __expf(x[c] - mx);
      const float lse = mx + __logf(se);
      const bool sv = (sl[k] != IGN);
      if (sv) { s_nll += lse - x[sl[k]]; s_cnt += 1.f; }
      // --- offset losses ---
      const float gx = ix[k] - cx[k];
      const float gy = iy[k] - cy[k];
      const float gz = iz[k] - cz[k];
      if (il[k] != IGN) {
        s_val  += 1.f;
        s_dist += fabsf(ox[k] - gx) + fabsf(oy[k] - gy) + fabsf(oz[k] - gz);
        const float gn = sqrtf(gx * gx + gy * gy + gz * gz) + 1e-8f;
        const float pn = sqrtf(ox[k] * ox[k] + oy[k] * oy[k] + oz[k] * oz[k]) + 1e-8f;
        s_dir += -((gx * ox[k] + gy * oy[k] + gz * oz[k]) / (gn * pn));
      }
    }
  }
  __shared__ float red[5][4];
  float vals[5] = { s_nll, s_cnt, s_dist, s_dir, s_val };
  const int lane = threadIdx.x & 63, wv = threadIdx.x >> 6;
  #pragma unroll
  for (int k = 0; k < 5; ++k) {
    const float t = waveSum(vals[k]);
    if (lane == 0) red[k][wv] = t;
  }
  __syncthreads();
  if (threadIdx.x < 5) {
    const float s = red[threadIdx.x][0] + red[threadIdx.x][1] + red[threadIdx.x][2] + red[threadIdx.x][3];
    atomicAdd(&g[threadIdx.x], (double)s);
  }
}

// ---------------------------------------------------------------------------
// K3: mask dice/BCE partials. Branchless float4 streaming; per-instance flags
// recomputed inline (histograms are tiny, L2-resident).
// ---------------------------------------------------------------------------
template <bool USE_META>
__global__ __launch_bounds__(256) void k_mask(const float* __restrict__ logits,
                                              const unsigned short* __restrict__ meta,
                                              const int* __restrict__ obj_idx,
                                              const int* __restrict__ inst_lab,
                                              const int* __restrict__ sem_lab,
                                              const int* __restrict__ batch_ids,
                                              const int* __restrict__ mode,
                                              const int* __restrict__ hist_full,
                                              const int* __restrict__ hist_mask,
                                              const int* __restrict__ inst_batch_ids,
                                              const int* __restrict__ inst_seg,
                                              double* __restrict__ i_inter,
                                              double* __restrict__ i_up,
                                              double* __restrict__ i_ug,
                                              double* __restrict__ i_wbs,
                                              double* __restrict__ i_sn) {
  const int i = blockIdx.y;
  const int mode_i = mode[i];
  const int bi     = inst_batch_ids[i];
  const int seg    = inst_seg[i];
  const bool skip  = (mode_i == 0) || (seg <= 3);
  const float num  = (float)hist_mask[bi * LW + mode_i];
  const float den  = (float)hist_full[bi * LW + mode_i];
  const float cover = (den > 0.f) ? (num / den) : 0.f;
  const bool pos   = (!skip) && (cover > 0.3f);

  float inter = 0.f, up = 0.f, ug = 0.f, wbs = 0.f, sn = 0.f;

  if (USE_META) {
    const float4* row4 = reinterpret_cast<const float4*>(logits + (size_t)i * M_PTS);
    const ushort4* m4  = reinterpret_cast<const ushort4*>(meta);
    const int nq = M_PTS / 4;
    for (int q = blockIdx.x * blockDim.x + threadIdx.x; q < nq; q += gridDim.x * blockDim.x) {
      const float4  x4 = row4[q];
      const ushort4 d4 = m4[q];
      const float xs[4] = { x4.x, x4.y, x4.z, x4.w };
      const int   ds[4] = { d4.x, d4.y, d4.z, d4.w };
      #pragma unroll
      for (int k = 0; k < 4; ++k) {
        const int md = ds[k];
        const int ml = md & 0xFF;
        const int sm = (md >> 8) & 31;
        const int b  = (md >> 13) & 3;
        const bool w  = (b == bi) && (skip || (sm == seg));
        const bool gt = pos && (ml == mode_i);
        const float x  = xs[k];
        const float e  = __expf(-fabsf(x));            // exp(-|x|)
        const float r  = __builtin_amdgcn_rcpf(1.f + e);
        const float pr = (x >= 0.f) ? r : e * r;       // sigmoid(x)
        const float sp = fmaxf(x, 0.f) + __logf(1.f + e);  // softplus(x)
        const float wf = w ? 1.f : 0.f;
        const float gf = gt ? 1.f : 0.f;
        up    += wf * pr * pr;
        wbs   += wf;
        sn    += wf * (sp - gf * x);
        inter += wf * gf * pr;
        ug    += wf * gf;
      }
    }
  } else {
    const float* row = logits + (size_t)i * M_PTS;
    for (int j = blockIdx.x * blockDim.x + threadIdx.x; j < M_PTS; j += gridDim.x * blockDim.x) {
      const int o  = obj_idx[j];
      const int il = inst_lab[o];
      const int ml = (il == IGN) ? 0 : (il + 1);
      const int sm = sem_lab[o];
      const int b  = batch_ids[j];
      const bool w  = (b == bi) && (skip || (sm == seg));
      const bool gt = pos && (ml == mode_i);
      const float x  = row[j];
      const float e  = __expf(-fabsf(x));
      const float r  = __builtin_amdgcn_rcpf(1.f + e);
      const float pr = (x >= 0.f) ? r : e * r;
      const float sp = fmaxf(x, 0.f) + __logf(1.f + e);
      const float wf = w ? 1.f : 0.f;
      const float gf = gt ? 1.f : 0.f;
      up    += wf * pr * pr;
      wbs   += wf;
      sn    += wf * (sp - gf * x);
      inter += wf * gf * pr;
      ug    += wf * gf;
    }
  }

  __shared__ float red[5][4];
  float vals[5] = { inter, up, ug, wbs, sn };
  const int lane = threadIdx.x & 63, wv = threadIdx.x >> 6;
  #pragma unroll
  for (int k = 0; k < 5; ++k) {
    const float t = waveSum(vals[k]);
    if (lane == 0) red[k][wv] = t;
  }
  __syncthreads();
  if (threadIdx.x < 5) {
    const float s = red[threadIdx.x][0] + red[threadIdx.x][1] + red[threadIdx.x][2] + red[threadIdx.x][3];
    double* dst = (threadIdx.x == 0) ? (i_inter + i)
                : (threadIdx.x == 1) ? (i_up + i)
                : (threadIdx.x == 2) ? (i_ug + i)
                : (threadIdx.x == 3) ? (i_wbs + i)
                                     : (i_sn + i);
    atomicAdd(dst, (double)s);
  }
}

// ---------------------------------------------------------------------------
// K4: combine everything into the scalar loss
// ---------------------------------------------------------------------------
__global__ void k_final(const double* __restrict__ g,
                        const double* __restrict__ i_inter,
                        const double* __restrict__ i_up,
                        const double* __restrict__ i_ug,
                        const double* __restrict__ i_wbs,
                        const double* __restrict__ i_sn,
                        const int* __restrict__ mode,
                        const int* __restrict__ inst_seg,
                        const int* __restrict__ epoch,
                        float* __restrict__ out) {
  if (threadIdx.x != 0 || blockIdx.x != 0) return;
  double loss = g[0] / fmax(g[1], 1.0);            // semantic
  const double vsum = g[4] + 1e-6;
  loss += g[2] / vsum + g[3] / vsum;               // offset norm + dir
  if (epoch[0] > PREP) {
    double sn = 0.0, wsum = 0.0, dice = 0.0, dcnt = 0.0;
    for (int i = 0; i < N_INST; ++i) {
      wsum += i_wbs[i];
      sn   += i_sn[i];
      const bool skip = (mode[i] == 0) || (inst_seg[i] <= 3);
      if (!skip && i_wbs[i] > 0.0) {
        const double un = i_up[i] + i_ug[i] + 1e-5;
        dice += 1.0 - 2.0 * i_inter[i] / un;
        dcnt += 1.0;
      }
    }
    loss += sn / (wsum + 1e-6) + dice / (dcnt + 1e-6);
  }
  out[0] = (float)loss;
}

} // anonymous namespace

extern "C" void kernel_launch(void* const* d_in, const int* in_sizes, int n_in,
                              void* d_out, int out_size, void* d_ws, size_t ws_size,
                              hipStream_t stream) {
  const float* semantic_scores  = (const float*)d_in[0];
  const float* pt_offsets       = (const float*)d_in[1];
  const float* instance_info    = (const float*)d_in[2];
  const float* coords           = (const float*)d_in[3];
  const float* mask_logits      = (const float*)d_in[4];
  const int*   semantic_labels  = (const int*)d_in[5];
  const int*   instance_labels  = (const int*)d_in[6];
  const int*   object_idxs      = (const int*)d_in[7];
  const int*   proposals_idx    = (const int*)d_in[8];
  const int*   proposals_off    = (const int*)d_in[9];
  const int*   inst_batch_ids   = (const int*)d_in[10];
  const int*   batch_ids        = (const int*)d_in[11];
  const int*   batch_offsets    = (const int*)d_in[12];
  const int*   inst_seg         = (const int*)d_in[13];
  const int*   epoch            = (const int*)d_in[14];
  float* out = (float*)d_out;

  char* w = (char*)d_ws;
  double* g        = (double*)(w + OFF_G);
  double* i_inter  = (double*)(w + OFF_INTER);
  double* i_up     = (double*)(w + OFF_UP);
  double* i_ug     = (double*)(w + OFF_UG);
  double* i_wbs    = (double*)(w + OFF_WBS);
  double* i_sn     = (double*)(w + OFF_SN);
  int* hist_full   = (int*)(w + OFF_HFULL);
  int* hist_mask   = (int*)(w + OFF_HMASK);
  int* mode        = (int*)(w + OFF_MODE);
  unsigned short* meta = (unsigned short*)(w + OFF_META);

  const bool use_meta = (ws_size >= WS_REQUIRED);

  hipMemsetAsync(d_ws, 0, ZERO_BYTES, stream);

  k_prep<<<PREP_BLOCKS, 256, 0, stream>>>(proposals_idx, proposals_off, instance_labels,
                                          semantic_labels, object_idxs, batch_ids,
                                          batch_offsets, mode, hist_mask, hist_full,
                                          meta, use_meta ? 1 : 0);

  k_point<<<(N_PTS / 4 + 255) / 256, 256, 0, stream>>>(semantic_scores, pt_offsets,
                                                       instance_info, coords,
                                                       semantic_labels, instance_labels, g);

  dim3 mgrid(40, N_INST);
  if (use_meta) {
    k_mask<true><<<mgrid, 256, 0, stream>>>(mask_logits, meta, object_idxs, instance_labels,
                                            semantic_labels, batch_ids, mode, hist_full,
                                            hist_mask, inst_batch_ids, inst_seg,
                                            i_inter, i_up, i_ug, i_wbs, i_sn);
  } else {
    k_mask<false><<<mgrid, 256, 0, stream>>>(mask_logits, meta, object_idxs, instance_labels,
                                             semantic_labels, batch_ids, mode, hist_full,
                                             hist_mask, inst_batch_ids, inst_seg,
                                             i_inter, i_up, i_ug, i_wbs, i_sn);
  }
  k_final<<<1, 64, 0, stream>>>(g, i_inter, i_up, i_ug, i_wbs, i_sn, mode, inst_seg, epoch, out);
}

// Round 4
// 296.996 us; speedup vs baseline: 1.5049x; 1.2157x over previous
//
#include <hip/hip_runtime.h>
#include <math.h>

namespace {

constexpr int N_PTS  = 1000000;
constexpr int C_CLS  = 20;
constexpr int N_B    = 4;
constexpr int L_LAB  = 200;
constexpr int LW     = L_LAB + 1;   // 201
constexpr int N_INST = 64;
constexpr int M_PTS  = 300000;
constexpr int T_PROP = 320000;
constexpr int IGN    = -100;
constexpr int PREP   = 128;

// ---- workspace layout (bytes) ----
constexpr size_t OFF_G      = 0;       // 5 doubles (reserve 64B)
constexpr size_t OFF_INTER  = 64;      // 64 doubles each
constexpr size_t OFF_UP     = 576;
constexpr size_t OFF_UG     = 1088;
constexpr size_t OFF_WBS    = 1600;
constexpr size_t OFF_SN     = 2112;
constexpr size_t OFF_HFULL  = 2624;    // 804 ints
constexpr size_t OFF_HMASK  = 5840;    // 804 ints
constexpr size_t OFF_IHIST  = 9056;    // 64*201 ints = 51456 B
constexpr size_t OFF_FLAGS  = 60512;   // 64 ints
constexpr size_t ZERO_BYTES = 60768;
constexpr size_t OFF_META   = 60800;   // 300000 ushorts
constexpr size_t WS_REQUIRED = OFF_META + (size_t)M_PTS * 2;

__device__ __forceinline__ float waveSumF(float v) {
  #pragma unroll
  for (int off = 32; off > 0; off >>= 1) v += __shfl_down(v, off, 64);
  return v;
}
__device__ __forceinline__ int waveMaxI(int v) {
  #pragma unroll
  for (int off = 32; off > 0; off >>= 1) v = max(v, __shfl_down(v, off, 64));
  return v;
}

// ---------------------------------------------------------------------------
// K_A: one dispatch, four independent jobs split by blockIdx.x.
//   [0, 1024)        : per-point losses (semantic NLL + offset norm/dir)
//   [1024, 1280)     : hist_full[B][LW] over N points (int4 scan, LDS hist)
//   [1280, 1536)     : proposal histogram -> inst_hist[64][LW] (global atomics)
//   [1536, 1792)     : hist_mask[B][LW] over M points + meta16 (batched gathers)
// ---------------------------------------------------------------------------
constexpr int PB_PT   = 1024;
constexpr int PB_HF   = 256;
constexpr int PB_PROP = 256;
constexpr int PB_HM   = 256;
constexpr int A_BLOCKS = PB_PT + PB_HF + PB_PROP + PB_HM;

__global__ __launch_bounds__(256) void k_A(const float* __restrict__ scores,
                                           const float* __restrict__ pt_off,
                                           const float* __restrict__ info,
                                           const float* __restrict__ coords,
                                           const int* __restrict__ sem_lab,
                                           const int* __restrict__ inst_lab,
                                           const int* __restrict__ obj_idx,
                                           const int* __restrict__ batch_ids,
                                           const int* __restrict__ prop_idx,
                                           const int* __restrict__ prop_off,
                                           const int* __restrict__ batch_off,
                                           double* __restrict__ g,
                                           int* __restrict__ hist_full,
                                           int* __restrict__ hist_mask,
                                           int* __restrict__ inst_hist,
                                           unsigned short* __restrict__ meta,
                                           int write_meta) {
  __shared__ int sh[N_B * LW];
  const int bx = blockIdx.x;

  if (bx < PB_PT) {
    // ================= per-point losses =================
    float s_nll = 0.f, s_cnt = 0.f, s_dist = 0.f, s_dir = 0.f, s_val = 0.f;
    const int gid = bx * blockDim.x + threadIdx.x;   // group of 4 points
    const int p0  = gid * 4;
    if (p0 < N_PTS) {
      const int4 sl4 = *reinterpret_cast<const int4*>(sem_lab + p0);
      const int4 il4 = *reinterpret_cast<const int4*>(inst_lab + p0);
      const float4* c4 = reinterpret_cast<const float4*>(coords + (size_t)p0 * 3);
      const float4 ca = c4[0], cb = c4[1], cc = c4[2];
      const float4* o4 = reinterpret_cast<const float4*>(pt_off + (size_t)p0 * 3);
      const float4 oa = o4[0], ob = o4[1], oc = o4[2];
      const float4* i4 = reinterpret_cast<const float4*>(info + (size_t)p0 * 9);
      const float4 f0 = i4[0], f2 = i4[2], f4 = i4[4], f5 = i4[5], f6 = i4[6], f7 = i4[7];
      const float cx[4] = { ca.x, ca.w, cb.z, cc.y };
      const float cy[4] = { ca.y, cb.x, cb.w, cc.z };
      const float cz[4] = { ca.z, cb.y, cc.x, cc.w };
      const float ox[4] = { oa.x, oa.w, ob.z, oc.y };
      const float oy[4] = { oa.y, ob.x, ob.w, oc.z };
      const float oz[4] = { oa.z, ob.y, oc.x, oc.w };
      const float ix[4] = { f0.x, f2.y, f4.z, f6.w };
      const float iy[4] = { f0.y, f2.z, f4.w, f7.x };
      const float iz[4] = { f0.z, f2.w, f5.x, f7.y };
      const int sl[4] = { sl4.x, sl4.y, sl4.z, sl4.w };
      const int il[4] = { il4.x, il4.y, il4.z, il4.w };
      #pragma unroll
      for (int k = 0; k < 4; ++k) {
        const int p = p0 + k;
        const float4* r4 = reinterpret_cast<const float4*>(scores + (size_t)p * C_CLS);
        float x[C_CLS];
        #pragma unroll
        for (int q = 0; q < C_CLS / 4; ++q) {
          const float4 v = r4[q];
          x[4 * q + 0] = v.x; x[4 * q + 1] = v.y; x[4 * q + 2] = v.z; x[4 * q + 3] = v.w;
        }
        float mx = x[0];
        #pragma unroll
        for (int c = 1; c < C_CLS; ++c) mx = fmaxf(mx, x[c]);
        float se = 0.f;
        #pragma unroll
        for (int c = 0; c < C_CLS; ++c) se += __expf(x[c] - mx);
        const float lse = mx + __logf(se);
        if (sl[k] != IGN) { s_nll += lse - x[sl[k]]; s_cnt += 1.f; }
        const float gx = ix[k] - cx[k];
        const float gy = iy[k] - cy[k];
        const float gz = iz[k] - cz[k];
        if (il[k] != IGN) {
          s_val  += 1.f;
          s_dist += fabsf(ox[k] - gx) + fabsf(oy[k] - gy) + fabsf(oz[k] - gz);
          const float gn = sqrtf(gx * gx + gy * gy + gz * gz) + 1e-8f;
          const float pn = sqrtf(ox[k] * ox[k] + oy[k] * oy[k] + oz[k] * oz[k]) + 1e-8f;
          s_dir += -((gx * ox[k] + gy * oy[k] + gz * oz[k]) / (gn * pn));
        }
      }
    }
    float* red = reinterpret_cast<float*>(sh);   // red[5][4]
    float vals[5] = { s_nll, s_cnt, s_dist, s_dir, s_val };
    const int lane = threadIdx.x & 63, wv = threadIdx.x >> 6;
    #pragma unroll
    for (int k = 0; k < 5; ++k) {
      const float t = waveSumF(vals[k]);
      if (lane == 0) red[k * 4 + wv] = t;
    }
    __syncthreads();
    if (threadIdx.x < 5) {
      const float s = red[threadIdx.x * 4 + 0] + red[threadIdx.x * 4 + 1] +
                      red[threadIdx.x * 4 + 2] + red[threadIdx.x * 4 + 3];
      atomicAdd(&g[threadIdx.x], (double)s);
    }
  } else if (bx < PB_PT + PB_HF) {
    // ================= hist_full over N points =================
    for (int t = threadIdx.x; t < N_B * LW; t += blockDim.x) sh[t] = 0;
    __syncthreads();
    const int b1 = batch_off[1], b2 = batch_off[2], b3 = batch_off[3];
    const int blk = bx - PB_PT;
    const int4* il4p = reinterpret_cast<const int4*>(inst_lab);
    const int nq = N_PTS / 4;
    for (int q = blk * blockDim.x + threadIdx.x; q < nq; q += PB_HF * blockDim.x) {
      const int4 v = il4p[q];
      const int p = q * 4;
      const int ils[4] = { v.x, v.y, v.z, v.w };
      #pragma unroll
      for (int k = 0; k < 4; ++k) {
        const int lab = (ils[k] == IGN) ? 0 : (ils[k] + 1);
        const int pp = p + k;
        int pb = 0;
        if (pp >= b1) pb = 1;
        if (pp >= b2) pb = 2;
        if (pp >= b3) pb = 3;
        atomicAdd(&sh[pb * LW + lab], 1);
      }
    }
    __syncthreads();
    for (int t = threadIdx.x; t < N_B * LW; t += blockDim.x)
      if (sh[t]) atomicAdd(&hist_full[t], sh[t]);
  } else if (bx < PB_PT + PB_HF + PB_PROP) {
    // ================= proposal histogram -> inst_hist (global atomics) ======
    if (threadIdx.x <= N_INST) sh[threadIdx.x] = prop_off[threadIdx.x];  // 65 ints
    __syncthreads();
    const int blk = bx - PB_PT - PB_HF;
    const int4* pi4 = reinterpret_cast<const int4*>(prop_idx);  // 2 proposals per int4
    const int nq = T_PROP / 2;   // index in int4 units over (T,2) int pairs
    for (int q = blk * blockDim.x + threadIdx.x; q < nq; q += PB_PROP * blockDim.x) {
      const int4 v = pi4[q];     // proposals 2q (y) and 2q+1 (w)
      const int t0 = 2 * q, t1 = 2 * q + 1;
      const int il0 = inst_lab[v.y];
      const int il1 = inst_lab[v.w];
      // binary search: first idx with prop_off > t  (prop_off[0]=0, [64]=T)
      int lo0 = 0, hi0 = N_INST + 1, lo1 = 0, hi1 = N_INST + 1;
      #pragma unroll
      for (int s = 0; s < 7; ++s) {
        const int m0 = (lo0 + hi0) >> 1;
        if (m0 <= N_INST && sh[m0] <= t0) lo0 = m0 + 1; else hi0 = m0;
        const int m1 = (lo1 + hi1) >> 1;
        if (m1 <= N_INST && sh[m1] <= t1) lo1 = m1 + 1; else hi1 = m1;
      }
      const int seg0 = min(lo0 - 1, N_INST - 1);
      const int seg1 = min(lo1 - 1, N_INST - 1);
      const int lab0 = (il0 == IGN) ? 0 : (il0 + 1);
      const int lab1 = (il1 == IGN) ? 0 : (il1 + 1);
      atomicAdd(&inst_hist[seg0 * LW + lab0], 1);
      atomicAdd(&inst_hist[seg1 * LW + lab1], 1);
    }
  } else {
    // ================= hist_mask over M points + meta =================
    for (int t = threadIdx.x; t < N_B * LW; t += blockDim.x) sh[t] = 0;
    __syncthreads();
    const int blk = bx - PB_PT - PB_HF - PB_PROP;
    const int4* oi4 = reinterpret_cast<const int4*>(obj_idx);
    const int4* bi4 = reinterpret_cast<const int4*>(batch_ids);
    ushort4* m4 = reinterpret_cast<ushort4*>(meta);
    const int nq = M_PTS / 4;
    for (int q = blk * blockDim.x + threadIdx.x; q < nq; q += PB_HM * blockDim.x) {
      const int4 o = oi4[q];
      const int4 b = bi4[q];
      // 8 independent gathers issued before any use
      const int il0 = inst_lab[o.x], il1 = inst_lab[o.y],
                il2 = inst_lab[o.z], il3 = inst_lab[o.w];
      const int sm0 = sem_lab[o.x], sm1 = sem_lab[o.y],
                sm2 = sem_lab[o.z], sm3 = sem_lab[o.w];
      const int ml0 = (il0 == IGN) ? 0 : (il0 + 1);
      const int ml1 = (il1 == IGN) ? 0 : (il1 + 1);
      const int ml2 = (il2 == IGN) ? 0 : (il2 + 1);
      const int ml3 = (il3 == IGN) ? 0 : (il3 + 1);
      atomicAdd(&sh[b.x * LW + ml0], 1);
      atomicAdd(&sh[b.y * LW + ml1], 1);
      atomicAdd(&sh[b.z * LW + ml2], 1);
      atomicAdd(&sh[b.w * LW + ml3], 1);
      if (write_meta) {
        ushort4 mm;
        mm.x = (unsigned short)(ml0 | (sm0 << 8) | (b.x << 13));
        mm.y = (unsigned short)(ml1 | (sm1 << 8) | (b.y << 13));
        mm.z = (unsigned short)(ml2 | (sm2 << 8) | (b.z << 13));
        mm.w = (unsigned short)(ml3 | (sm3 << 8) | (b.w << 13));
        m4[q] = mm;
      }
    }
    __syncthreads();
    for (int t = threadIdx.x; t < N_B * LW; t += blockDim.x)
      if (sh[t]) atomicAdd(&hist_mask[t], sh[t]);
  }
}

// ---------------------------------------------------------------------------
// K_ARGMAX: per-instance mode (first-index ties) + packed flags
//   flags: {mode[0:8], skip[8], pos[9], batch[10:12], seg[12:17]}
// ---------------------------------------------------------------------------
__global__ __launch_bounds__(256) void k_argmax(const int* __restrict__ inst_hist,
                                                const int* __restrict__ hist_full,
                                                const int* __restrict__ hist_mask,
                                                const int* __restrict__ inst_batch_ids,
                                                const int* __restrict__ inst_seg,
                                                int* __restrict__ flags) {
  __shared__ int red[4];
  const int i = blockIdx.x;
  const int t = threadIdx.x;
  int key = 0;   // (cnt << 8) | (255 - bin): max -> largest cnt, then smallest bin
  if (t < LW) {
    const int cnt = inst_hist[i * LW + t];
    key = (cnt << 8) | (255 - t);
  }
  key = waveMaxI(key);
  const int lane = t & 63, wv = t >> 6;
  if (lane == 0) red[wv] = key;
  __syncthreads();
  if (t == 0) {
    int k = max(max(red[0], red[1]), max(red[2], red[3]));
    const int m = 255 - (k & 0xFF);
    const int b = inst_batch_ids[i];
    const int seg = inst_seg[i];
    const bool skip = (m == 0) || (seg <= 3);
    const float num = (float)hist_mask[b * LW + m];
    const float den = (float)hist_full[b * LW + m];
    const float cover = (den > 0.f) ? (num / den) : 0.f;
    const bool pos = (!skip) && (cover > 0.3f);
    flags[i] = m | (skip ? 0x100 : 0) | (pos ? 0x200 : 0) | (b << 10) | (seg << 12);
  }
}

// ---------------------------------------------------------------------------
// K_MASK: branchless float4 streaming of logits, per-instance partials.
// ---------------------------------------------------------------------------
template <bool USE_META>
__global__ __launch_bounds__(256) void k_mask(const float* __restrict__ logits,
                                              const unsigned short* __restrict__ meta,
                                              const int* __restrict__ obj_idx,
                                              const int* __restrict__ inst_lab,
                                              const int* __restrict__ sem_lab,
                                              const int* __restrict__ batch_ids,
                                              const int* __restrict__ flags,
                                              double* __restrict__ i_inter,
                                              double* __restrict__ i_up,
                                              double* __restrict__ i_ug,
                                              double* __restrict__ i_wbs,
                                              double* __restrict__ i_sn) {
  const int i  = blockIdx.y;
  const int fl = flags[i];
  const int  mode_i = fl & 0xFF;
  const bool skip   = (fl >> 8) & 1;
  const bool pos    = (fl >> 9) & 1;
  const int  bi     = (fl >> 10) & 3;
  const int  seg    = (fl >> 12) & 31;

  float inter = 0.f, up = 0.f, ug = 0.f, wbs = 0.f, sn = 0.f;

  if (USE_META) {
    const float4* row4 = reinterpret_cast<const float4*>(logits + (size_t)i * M_PTS);
    const ushort4* m4  = reinterpret_cast<const ushort4*>(meta);
    const int nq = M_PTS / 4;
    for (int q = blockIdx.x * blockDim.x + threadIdx.x; q < nq; q += gridDim.x * blockDim.x) {
      const float4  x4 = row4[q];
      const ushort4 d4 = m4[q];
      const float xs[4] = { x4.x, x4.y, x4.z, x4.w };
      const int   ds[4] = { d4.x, d4.y, d4.z, d4.w };
      #pragma unroll
      for (int k = 0; k < 4; ++k) {
        const int md = ds[k];
        const int ml = md & 0xFF;
        const int sm = (md >> 8) & 31;
        const int b  = (md >> 13) & 3;
        const bool w  = (b == bi) && (skip || (sm == seg));
        const bool gt = pos && (ml == mode_i);
        const float x  = xs[k];
        const float e  = __expf(-fabsf(x));
        const float r  = __builtin_amdgcn_rcpf(1.f + e);
        const float pr = (x >= 0.f) ? r : e * r;            // sigmoid
        const float sp = fmaxf(x, 0.f) + __logf(1.f + e);   // softplus
        const float wf = w ? 1.f : 0.f;
        const float gf = gt ? 1.f : 0.f;
        up    += wf * pr * pr;
        wbs   += wf;
        sn    += wf * (sp - gf * x);
        inter += wf * gf * pr;
        ug    += wf * gf;
      }
    }
  } else {
    const float* row = logits + (size_t)i * M_PTS;
    for (int j = blockIdx.x * blockDim.x + threadIdx.x; j < M_PTS; j += gridDim.x * blockDim.x) {
      const int o  = obj_idx[j];
      const int il = inst_lab[o];
      const int ml = (il == IGN) ? 0 : (il + 1);
      const int sm = sem_lab[o];
      const int b  = batch_ids[j];
      const bool w  = (b == bi) && (skip || (sm == seg));
      const bool gt = pos && (ml == mode_i);
      const float x  = row[j];
      const float e  = __expf(-fabsf(x));
      const float r  = __builtin_amdgcn_rcpf(1.f + e);
      const float pr = (x >= 0.f) ? r : e * r;
      const float sp = fmaxf(x, 0.f) + __logf(1.f + e);
      const float wf = w ? 1.f : 0.f;
      const float gf = gt ? 1.f : 0.f;
      up    += wf * pr * pr;
      wbs   += wf;
      sn    += wf * (sp - gf * x);
      inter += wf * gf * pr;
      ug    += wf * gf;
    }
  }

  __shared__ float red[5][4];
  float vals[5] = { inter, up, ug, wbs, sn };
  const int lane = threadIdx.x & 63, wv = threadIdx.x >> 6;
  #pragma unroll
  for (int k = 0; k < 5; ++k) {
    const float t = waveSumF(vals[k]);
    if (lane == 0) red[k][wv] = t;
  }
  __syncthreads();
  if (threadIdx.x < 5) {
    const float s = red[threadIdx.x][0] + red[threadIdx.x][1] + red[threadIdx.x][2] + red[threadIdx.x][3];
    double* dst = (threadIdx.x == 0) ? (i_inter + i)
                : (threadIdx.x == 1) ? (i_up + i)
                : (threadIdx.x == 2) ? (i_ug + i)
                : (threadIdx.x == 3) ? (i_wbs + i)
                                     : (i_sn + i);
    atomicAdd(dst, (double)s);
  }
}

// ---------------------------------------------------------------------------
// K_FINAL
// ---------------------------------------------------------------------------
__global__ void k_final(const double* __restrict__ g,
                        const double* __restrict__ i_inter,
                        const double* __restrict__ i_up,
                        const double* __restrict__ i_ug,
                        const double* __restrict__ i_wbs,
                        const double* __restrict__ i_sn,
                        const int* __restrict__ flags,
                        const int* __restrict__ epoch,
                        float* __restrict__ out) {
  if (threadIdx.x != 0 || blockIdx.x != 0) return;
  double loss = g[0] / fmax(g[1], 1.0);            // semantic
  const double vsum = g[4] + 1e-6;
  loss += g[2] / vsum + g[3] / vsum;               // offset norm + dir
  if (epoch[0] > PREP) {
    double sn = 0.0, wsum = 0.0, dice = 0.0, dcnt = 0.0;
    for (int i = 0; i < N_INST; ++i) {
      wsum += i_wbs[i];
      sn   += i_sn[i];
      const bool skip = (flags[i] >> 8) & 1;
      if (!skip && i_wbs[i] > 0.0) {
        const double un = i_up[i] + i_ug[i] + 1e-5;
        dice += 1.0 - 2.0 * i_inter[i] / un;
        dcnt += 1.0;
      }
    }
    loss += sn / (wsum + 1e-6) + dice / (dcnt + 1e-6);
  }
  out[0] = (float)loss;
}

} // anonymous namespace

extern "C" void kernel_launch(void* const* d_in, const int* in_sizes, int n_in,
                              void* d_out, int out_size, void* d_ws, size_t ws_size,
                              hipStream_t stream) {
  const float* semantic_scores  = (const float*)d_in[0];
  const float* pt_offsets       = (const float*)d_in[1];
  const float* instance_info    = (const float*)d_in[2];
  const float* coords           = (const float*)d_in[3];
  const float* mask_logits      = (const float*)d_in[4];
  const int*   semantic_labels  = (const int*)d_in[5];
  const int*   instance_labels  = (const int*)d_in[6];
  const int*   object_idxs      = (const int*)d_in[7];
  const int*   proposals_idx    = (const int*)d_in[8];
  const int*   proposals_off    = (const int*)d_in[9];
  const int*   inst_batch_ids   = (const int*)d_in[10];
  const int*   batch_ids        = (const int*)d_in[11];
  const int*   batch_offsets    = (const int*)d_in[12];
  const int*   inst_seg         = (const int*)d_in[13];
  const int*   epoch            = (const int*)d_in[14];
  float* out = (float*)d_out;

  char* w = (char*)d_ws;
  double* g        = (double*)(w + OFF_G);
  double* i_inter  = (double*)(w + OFF_INTER);
  double* i_up     = (double*)(w + OFF_UP);
  double* i_ug     = (double*)(w + OFF_UG);
  double* i_wbs    = (double*)(w + OFF_WBS);
  double* i_sn     = (double*)(w + OFF_SN);
  int* hist_full   = (int*)(w + OFF_HFULL);
  int* hist_mask   = (int*)(w + OFF_HMASK);
  int* inst_hist   = (int*)(w + OFF_IHIST);
  int* flags       = (int*)(w + OFF_FLAGS);
  unsigned short* meta = (unsigned short*)(w + OFF_META);

  const bool use_meta = (ws_size >= WS_REQUIRED);

  (void)hipMemsetAsync(d_ws, 0, ZERO_BYTES, stream);

  k_A<<<A_BLOCKS, 256, 0, stream>>>(semantic_scores, pt_offsets, instance_info, coords,
                                    semantic_labels, instance_labels, object_idxs,
                                    batch_ids, proposals_idx, proposals_off, batch_offsets,
                                    g, hist_full, hist_mask, inst_hist, meta,
                                    use_meta ? 1 : 0);

  k_argmax<<<N_INST, 256, 0, stream>>>(inst_hist, hist_full, hist_mask,
                                       inst_batch_ids, inst_seg, flags);

  dim3 mgrid(40, N_INST);
  if (use_meta) {
    k_mask<true><<<mgrid, 256, 0, stream>>>(mask_logits, meta, object_idxs, instance_labels,
                                            semantic_labels, batch_ids, flags,
                                            i_inter, i_up, i_ug, i_wbs, i_sn);
  } else {
    k_mask<false><<<mgrid, 256, 0, stream>>>(mask_logits, meta, object_idxs, instance_labels,
                                             semantic_labels, batch_ids, flags,
                                             i_inter, i_up, i_ug, i_wbs, i_sn);
  }
  k_final<<<1, 64, 0, stream>>>(g, i_inter, i_up, i_ug, i_wbs, i_sn, flags, epoch, out);
}